// Round 1
// baseline (17.753 us; speedup 1.0000x reference)
//
#include <hip/hip_runtime.h>

namespace {
constexpr float kEps = 1e-6f;
constexpr int kNPix = 90000;                        // 300*300
constexpr int kBatch = 16;
constexpr int kPal = 30;
constexpr int kQuadsPerImg = kNPix / 4;             // 22500
constexpr int kTotalQuads = kBatch * kQuadsPerImg;  // 360000
constexpr int kBlock = 256;
constexpr int kGrid = (kTotalQuads + kBlock - 1) / kBlock;  // 1407
}  // namespace

// Stage 1: per-block partial sums of min-palette color distance.
__global__ __launch_bounds__(256) void nps_partial_kernel(
    const float* __restrict__ patch, const float* __restrict__ pal,
    float* __restrict__ partial) {
  // Palette is constant over HxW: color (p,c) lives at pal[(p*3+c)*kNPix].
  // Pre-fold the +EPS on diff:  x - col + EPS == x - (col - EPS).
  float colE[kPal][3];
#pragma unroll
  for (int p = 0; p < kPal; ++p)
#pragma unroll
    for (int c = 0; c < 3; ++c)
      colE[p][c] = pal[(p * 3 + c) * kNPix] - kEps;

  float acc = 0.f;
  const int stride = gridDim.x * blockDim.x;
  for (int qi = blockIdx.x * blockDim.x + threadIdx.x; qi < kTotalQuads;
       qi += stride) {
    const int b = qi / kQuadsPerImg;
    const int q = qi - b * kQuadsPerImg;
    const float* base = patch + (size_t)b * (3 * kNPix) + q * 4;
    const float4 vr = *reinterpret_cast<const float4*>(base);
    const float4 vg = *reinterpret_cast<const float4*>(base + kNPix);
    const float4 vb = *reinterpret_cast<const float4*>(base + 2 * kNPix);
    const float xs[4] = {vr.x, vr.y, vr.z, vr.w};
    const float ys[4] = {vg.x, vg.y, vg.z, vg.w};
    const float zs[4] = {vb.x, vb.y, vb.z, vb.w};
#pragma unroll
    for (int j = 0; j < 4; ++j) {
      float m = 3.4e38f;
#pragma unroll
      for (int p = 0; p < kPal; ++p) {
        const float d0 = xs[j] - colE[p][0];
        const float d1 = ys[j] - colE[p][1];
        const float d2 = zs[j] - colE[p][2];
        const float s = fmaf(d0, d0, fmaf(d1, d1, fmaf(d2, d2, kEps)));
        m = fminf(m, s);  // min of squared dists; sqrt is monotone
      }
      acc += sqrtf(m);    // single sqrt per pixel
    }
  }

  // Block reduction: wave shuffle, then LDS across the 4 waves.
#pragma unroll
  for (int off = 32; off > 0; off >>= 1) acc += __shfl_down(acc, off, 64);
  __shared__ float warp_sums[4];
  const int lane = threadIdx.x & 63;
  const int wid = threadIdx.x >> 6;
  if (lane == 0) warp_sums[wid] = acc;
  __syncthreads();
  if (threadIdx.x == 0)
    partial[blockIdx.x] =
        warp_sums[0] + warp_sums[1] + warp_sums[2] + warp_sums[3];
}

// Stage 2: deterministic final reduction (single block), scale by 1/size.
__global__ __launch_bounds__(256) void nps_finish_kernel(
    const float* __restrict__ partial, int n, float* __restrict__ out) {
  double acc = 0.0;
  for (int i = threadIdx.x; i < n; i += (int)blockDim.x)
    acc += (double)partial[i];
#pragma unroll
  for (int off = 32; off > 0; off >>= 1) acc += __shfl_down(acc, off, 64);
  __shared__ double warp_sums[4];
  const int lane = threadIdx.x & 63;
  const int wid = threadIdx.x >> 6;
  if (lane == 0) warp_sums[wid] = acc;
  __syncthreads();
  if (threadIdx.x == 0)
    out[0] = (float)((warp_sums[0] + warp_sums[1] + warp_sums[2] +
                      warp_sums[3]) *
                     (1.0 / 4320000.0));
}

extern "C" void kernel_launch(void* const* d_in, const int* in_sizes, int n_in,
                              void* d_out, int out_size, void* d_ws,
                              size_t ws_size, hipStream_t stream) {
  const float* patch = (const float*)d_in[0];  // [16,3,300,300] f32
  const float* pal = (const float*)d_in[1];    // [30,3,300,300] f32 (bcast colors)
  float* out = (float*)d_out;                  // scalar f32
  float* partial = (float*)d_ws;               // kGrid floats of scratch

  nps_partial_kernel<<<kGrid, kBlock, 0, stream>>>(patch, pal, partial);
  nps_finish_kernel<<<1, kBlock, 0, stream>>>(partial, kGrid, out);
}

// Round 2
// 13.208 us; speedup vs baseline: 1.3441x; 1.3441x over previous
//
#include <hip/hip_runtime.h>

namespace {
constexpr float kEps = 1e-6f;
constexpr int kNPix = 90000;   // 300*300
constexpr int kBatch = 16;
constexpr int kPal = 30;
constexpr int kPixPerThread = 8;
constexpr int kTasksPerImg = kNPix / kPixPerThread;   // 11250
constexpr int kTotalTasks = kBatch * kTasksPerImg;    // 180000
constexpr int kBlock = 256;
constexpr int kGrid = (kTotalTasks + kBlock - 1) / kBlock;  // 704 (=8*88)
}  // namespace

// Stage 1: per-block partial sums of min-palette color distance.
// dist^2 + eps = (x^2+y^2+z^2) + min_p( -2a'x -2b'y -2c'z + (|a'|^2 + eps) )
// with a' = a - eps (folds the reference's "+EPS on diff").
__global__ __launch_bounds__(256) void nps_partial_kernel(
    const float* __restrict__ patch, const float* __restrict__ pal,
    float* __restrict__ partial) {
  __shared__ float4 lpal[kPal];
  if (threadIdx.x < kPal) {
    const int p = threadIdx.x;
    const float a = pal[(p * 3 + 0) * kNPix] - kEps;
    const float b = pal[(p * 3 + 1) * kNPix] - kEps;
    const float c = pal[(p * 3 + 2) * kNPix] - kEps;
    lpal[p] = make_float4(-2.f * a, -2.f * b, -2.f * c,
                          fmaf(a, a, fmaf(b, b, fmaf(c, c, kEps))));
  }
  __syncthreads();

  float acc = 0.f;
  const int stride = gridDim.x * blockDim.x;
  for (int ti = blockIdx.x * blockDim.x + threadIdx.x; ti < kTotalTasks;
       ti += stride) {
    const int b = ti / kTasksPerImg;
    const int r = ti - b * kTasksPerImg;
    const float* base = patch + (size_t)b * (3 * kNPix) + r * kPixPerThread;
    const float4 x0 = *reinterpret_cast<const float4*>(base);
    const float4 x1 = *reinterpret_cast<const float4*>(base + 4);
    const float4 y0 = *reinterpret_cast<const float4*>(base + kNPix);
    const float4 y1 = *reinterpret_cast<const float4*>(base + kNPix + 4);
    const float4 z0 = *reinterpret_cast<const float4*>(base + 2 * kNPix);
    const float4 z1 = *reinterpret_cast<const float4*>(base + 2 * kNPix + 4);
    const float px[8] = {x0.x, x0.y, x0.z, x0.w, x1.x, x1.y, x1.z, x1.w};
    const float py[8] = {y0.x, y0.y, y0.z, y0.w, y1.x, y1.y, y1.z, y1.w};
    const float pz[8] = {z0.x, z0.y, z0.z, z0.w, z1.x, z1.y, z1.z, z1.w};

    float sx[8], md[8];
#pragma unroll
    for (int j = 0; j < 8; ++j) {
      sx[j] = fmaf(px[j], px[j], fmaf(py[j], py[j], pz[j] * pz[j]));
      md[j] = 3.4e38f;
    }
#pragma unroll 6
    for (int p = 0; p < kPal; ++p) {
      const float4 cf = lpal[p];
#pragma unroll
      for (int j = 0; j < 8; ++j) {
        md[j] = fminf(md[j], fmaf(px[j], cf.x,
                                  fmaf(py[j], cf.y, fmaf(pz[j], cf.z, cf.w))));
      }
    }
#pragma unroll
    for (int j = 0; j < 8; ++j) acc += sqrtf(sx[j] + md[j]);
  }

  // Block reduction: wave shuffle, then LDS across the 4 waves.
#pragma unroll
  for (int off = 32; off > 0; off >>= 1) acc += __shfl_down(acc, off, 64);
  __shared__ float warp_sums[4];
  const int lane = threadIdx.x & 63;
  const int wid = threadIdx.x >> 6;
  if (lane == 0) warp_sums[wid] = acc;
  __syncthreads();
  if (threadIdx.x == 0)
    partial[blockIdx.x] =
        warp_sums[0] + warp_sums[1] + warp_sums[2] + warp_sums[3];
}

// Stage 2: deterministic final reduction (single block), scale by 1/size.
__global__ __launch_bounds__(256) void nps_finish_kernel(
    const float* __restrict__ partial, int n, float* __restrict__ out) {
  double acc = 0.0;
  for (int i = threadIdx.x; i < n; i += (int)blockDim.x)
    acc += (double)partial[i];
#pragma unroll
  for (int off = 32; off > 0; off >>= 1) acc += __shfl_down(acc, off, 64);
  __shared__ double warp_sums[4];
  const int lane = threadIdx.x & 63;
  const int wid = threadIdx.x >> 6;
  if (lane == 0) warp_sums[wid] = acc;
  __syncthreads();
  if (threadIdx.x == 0)
    out[0] = (float)((warp_sums[0] + warp_sums[1] + warp_sums[2] +
                      warp_sums[3]) *
                     (1.0 / 4320000.0));
}

extern "C" void kernel_launch(void* const* d_in, const int* in_sizes, int n_in,
                              void* d_out, int out_size, void* d_ws,
                              size_t ws_size, hipStream_t stream) {
  const float* patch = (const float*)d_in[0];  // [16,3,300,300] f32
  const float* pal = (const float*)d_in[1];    // [30,3,300,300] f32 (bcast colors)
  float* out = (float*)d_out;                  // scalar f32
  float* partial = (float*)d_ws;               // kGrid floats of scratch

  nps_partial_kernel<<<kGrid, kBlock, 0, stream>>>(patch, pal, partial);
  nps_finish_kernel<<<1, kBlock, 0, stream>>>(partial, kGrid, out);
}